// Round 11
// baseline (493.851 us; speedup 1.0000x reference)
//
#include <hip/hip_runtime.h>
#include <stdint.h>

// Problem geometry (fixed by reference): x [32,96,128,128] fp32, SPACING=2.
static constexpr uint32_t kBC       = 32u * 96u;          // 3072 (b,c) slices
static constexpr uint32_t kR        = 64u * 64u;          // 4096 regions per slice
static constexpr uint32_t kImg      = 128u * 128u;        // 16384
static constexpr uint32_t kSparseN  = kBC * kImg;         // 50331648
static constexpr uint32_t kPooledN  = kBC * kR;           // 12582912

#define EPSF 1e-8f
#define GAP_THR2 2e-3f   // log2-scale top2 gap below which region is re-done exactly
#define SPREAD_THR 7.0f  // m - min(v,0) above which eps-term in log(p+eps) matters
#define TMIN_THR 1e-5f   // belt-and-braces guard on gumbel inner value

__device__ __forceinline__ uint32_t rotl32(uint32_t v, int r) {
    return (v << r) | (v >> (32 - r));   // -> v_alignbit_b32
}

// JAX threefry2x32 with key = (0,1)  [jax.random.key(1)], 20 rounds.
__device__ __forceinline__ void threefry2x32_01(uint32_t x0, uint32_t x1,
                                                uint32_t& o0, uint32_t& o1) {
    const uint32_t ks0 = 0u;
    const uint32_t ks1 = 1u;
    const uint32_t ks2 = 0x1BD11BDAu ^ 0u ^ 1u;  // 0x1BD11BDB
    x0 += ks0; x1 += ks1;
    x0 += x1; x1 = rotl32(x1, 13); x1 ^= x0;
    x0 += x1; x1 = rotl32(x1, 15); x1 ^= x0;
    x0 += x1; x1 = rotl32(x1, 26); x1 ^= x0;
    x0 += x1; x1 = rotl32(x1,  6); x1 ^= x0;
    x0 += ks1; x1 += ks2 + 1u;
    x0 += x1; x1 = rotl32(x1, 17); x1 ^= x0;
    x0 += x1; x1 = rotl32(x1, 29); x1 ^= x0;
    x0 += x1; x1 = rotl32(x1, 16); x1 ^= x0;
    x0 += x1; x1 = rotl32(x1, 24); x1 ^= x0;
    x0 += ks2; x1 += ks0 + 2u;
    x0 += x1; x1 = rotl32(x1, 13); x1 ^= x0;
    x0 += x1; x1 = rotl32(x1, 15); x1 ^= x0;
    x0 += x1; x1 = rotl32(x1, 26); x1 ^= x0;
    x0 += x1; x1 = rotl32(x1,  6); x1 ^= x0;
    x0 += ks0; x1 += ks1 + 3u;
    x0 += x1; x1 = rotl32(x1, 17); x1 ^= x0;
    x0 += x1; x1 = rotl32(x1, 29); x1 ^= x0;
    x0 += x1; x1 = rotl32(x1, 16); x1 ^= x0;
    x0 += x1; x1 = rotl32(x1, 24); x1 ^= x0;
    x0 += ks1; x1 += ks2 + 4u;
    x0 += x1; x1 = rotl32(x1, 13); x1 ^= x0;
    x0 += x1; x1 = rotl32(x1, 15); x1 ^= x0;
    x0 += x1; x1 = rotl32(x1, 26); x1 ^= x0;
    x0 += x1; x1 = rotl32(x1,  6); x1 ^= x0;
    x0 += ks2; x1 += ks0 + 5u;
    o0 = x0; o1 = x1;
}

// JAX partitionable threefry bits: bits(i) = o0 ^ o1 of threefry2x32(key,(0,i)).
__device__ __forceinline__ uint32_t jax_bits_partitionable(uint32_t i) {
    uint32_t o0, o1;
    threefry2x32_01(0u, i, o0, o1);
    return o0 ^ o1;
}

// uniform [0,1) from bits — exact bit ops, shared by fast and exact paths.
__device__ __forceinline__ float uniform_from_bits(uint32_t bits) {
    uint32_t fb = (bits >> 9) | 0x3F800000u;
    return __uint_as_float(fb) - 1.0f;
}

// Raw hardware transcendentals (guaranteed v_log_f32 / v_exp_f32 / v_rcp_f32).
__device__ __forceinline__ float hw_log2(float x) { return __builtin_amdgcn_logf(x); }
__device__ __forceinline__ float hw_exp2(float x) { return __builtin_amdgcn_exp2f(x); }
__device__ __forceinline__ float hw_rcp (float x) { return __builtin_amdgcn_rcpf(x); }

// One 2x2 region, pure fast path. p/pooled via hw exp2+rcp (bf16-invisible err).
// Argmax in log2 scale with common terms cancelled:
//   z'_i = v_i*log2e - log2(t_i),  t_i = -ln(u_i+eps)+eps,  null: z'_4 = -log2(t_4)
// (reference z_i*log2e = z'_i + const). Regions where the decision is not
// provably safe (top2 gap < GAP_THR2, spread > SPREAD_THR amplifying the
// log(p+eps) eps-term, or t < TMIN_THR) get their index appended to wlist and
// are re-done bit-exactly by the fixup kernel.
__device__ __forceinline__ void do_region_v5(float v0, float v1, float v2, float v3,
                                             uint32_t rIdx,
                                             uint32_t* wcount, uint32_t* wlist, uint32_t cap,
                                             float& s0, float& s1, float& s2, float& s3,
                                             float& pooledv, float& winv) {
    const uint32_t jb = rIdx * 5u;
    float u0 = uniform_from_bits(jax_bits_partitionable(jb + 0u));
    float u1 = uniform_from_bits(jax_bits_partitionable(jb + 1u));
    float u2 = uniform_from_bits(jax_bits_partitionable(jb + 2u));
    float u3 = uniform_from_bits(jax_bits_partitionable(jb + 3u));
    float u4 = uniform_from_bits(jax_bits_partitionable(jb + 4u));

    const float L2E  = 1.44269504088896340736f;
    const float NLN2 = -0.69314718055994530942f;

    float m    = fmaxf(fmaxf(fmaxf(fmaxf(v0, v1), v2), v3), 0.0f);
    float vmin = fminf(fminf(v0, v1), fminf(v2, v3));
    float c0 = v0 * L2E, c1 = v1 * L2E, c2 = v2 * L2E, c3 = v3 * L2E;
    float cm = m * L2E;

    // ---- p values (outputs only; hw exp2 + rcp) ----
    float e0 = hw_exp2(c0 - cm);
    float e1 = hw_exp2(c1 - cm);
    float e2 = hw_exp2(c2 - cm);
    float e3 = hw_exp2(c3 - cm);
    float e4 = hw_exp2(0.0f - cm);
    float den = ((((e0 + e1) + e2) + e3) + e4) + EPSF;
    float rr  = hw_rcp(den);
    float p0 = e0 * rr;
    float p1 = e1 * rr;
    float p2 = e2 * rr;
    float p3 = e3 * rr;
    float p4 = e4 * rr;

    // ---- decision path (independent of exp/den chain) ----
    float t0 = fmaf(NLN2, hw_log2(u0 + EPSF), EPSF);
    float t1 = fmaf(NLN2, hw_log2(u1 + EPSF), EPSF);
    float t2 = fmaf(NLN2, hw_log2(u2 + EPSF), EPSF);
    float t3 = fmaf(NLN2, hw_log2(u3 + EPSF), EPSF);
    float t4 = fmaf(NLN2, hw_log2(u4 + EPSF), EPSF);
    float z0 = c0 - hw_log2(t0);
    float z1 = c1 - hw_log2(t1);
    float z2 = c2 - hw_log2(t2);
    float z3 = c3 - hw_log2(t3);
    float z4 = 0.0f - hw_log2(t4);
    float tmin = fminf(fminf(fminf(t0, t1), fminf(t2, t3)), t4);

    // top-1 (first occurrence) + runner-up
    int w = 0; float best = z0; float second = -3.4e38f;
    if (z1 > best) { second = best; best = z1; w = 1; } else { second = z1; }
    if (z2 > best) { second = best; best = z2; w = 2; } else if (z2 > second) { second = z2; }
    if (z3 > best) { second = best; best = z3; w = 3; } else if (z3 > second) { second = z3; }
    if (z4 > best) { second = best; best = z4; w = 4; } else if (z4 > second) { second = z4; }

    bool flag = (best - second < GAP_THR2) ||
                (m - fminf(vmin, 0.0f) > SPREAD_THR) ||
                (tmin < TMIN_THR);
    if (flag) {
        uint32_t slot = atomicAdd(wcount, 1u);
        if (slot < cap) wlist[slot] = rIdx;
    }

    float wp = (w == 0) ? p0 : (w == 1) ? p1 : (w == 2) ? p2 : (w == 3) ? p3 : p4;
    s0 = (w == 0) ? wp : 0.0f;
    s1 = (w == 1) ? wp : 0.0f;
    s2 = (w == 2) ? wp : 0.0f;
    s3 = (w == 3) ? wp : 0.0f;
    pooledv = ((p0 + p1) + p2) + p3;
    winv = (float)w;
}

// Each thread: 4 adjacent regions (2 rows x 8 cols) of one bc slice.
__global__ __launch_bounds__(256, 6) void mmp_kernel(const float* __restrict__ x,
                                                     float* __restrict__ sparse,
                                                     float* __restrict__ pooled,
                                                     float* __restrict__ winner,
                                                     uint32_t* __restrict__ wcount,
                                                     uint32_t* __restrict__ wlist,
                                                     uint32_t cap) {
    const uint32_t t  = blockIdx.x * 256u + threadIdx.x;
    const uint32_t pj = t & 15u;           // 8-col group (cols 8*pj .. 8*pj+7)
    const uint32_t pi = (t >> 4) & 63u;    // region row (img rows 2*pi, 2*pi+1)
    const uint32_t bc = t >> 10;           // [0, 3072)

    const float* xp = x + (size_t)bc * kImg + pi * 256u + pj * 8u;
    float4 a0 = *(const float4*)(xp);          // row 2pi,   cols 0..3 of group
    float4 a1 = *(const float4*)(xp + 4);      // row 2pi,   cols 4..7
    float4 b0 = *(const float4*)(xp + 128);    // row 2pi+1, cols 0..3
    float4 b1 = *(const float4*)(xp + 132);    // row 2pi+1, cols 4..7

    const uint32_t r0 = bc * kR + pi * 64u + pj * 4u;   // first region index
    float* sp = sparse + (size_t)bc * kImg + pi * 256u + pj * 8u;

    float s0, s1, s2, s3;
    float pool0, pool1, pool2, pool3, win0, win1, win2, win3;

    do_region_v5(a0.x, a0.y, b0.x, b0.y, r0 + 0u, wcount, wlist, cap, s0, s1, s2, s3, pool0, win0);
    *(float2*)(sp)       = make_float2(s0, s1);
    *(float2*)(sp + 128) = make_float2(s2, s3);
    do_region_v5(a0.z, a0.w, b0.z, b0.w, r0 + 1u, wcount, wlist, cap, s0, s1, s2, s3, pool1, win1);
    *(float2*)(sp + 2)   = make_float2(s0, s1);
    *(float2*)(sp + 130) = make_float2(s2, s3);
    do_region_v5(a1.x, a1.y, b1.x, b1.y, r0 + 2u, wcount, wlist, cap, s0, s1, s2, s3, pool2, win2);
    *(float2*)(sp + 4)   = make_float2(s0, s1);
    *(float2*)(sp + 132) = make_float2(s2, s3);
    do_region_v5(a1.z, a1.w, b1.z, b1.w, r0 + 3u, wcount, wlist, cap, s0, s1, s2, s3, pool3, win3);
    *(float2*)(sp + 6)   = make_float2(s0, s1);
    *(float2*)(sp + 134) = make_float2(s2, s3);

    *(float4*)(pooled + r0) = make_float4(pool0, pool1, pool2, pool3);
    *(float4*)(winner + r0) = make_float4(win0, win1, win2, win3);
}

// Fixup: re-run flagged regions with the reference's exact OCML chain.
__global__ __launch_bounds__(256) void mmp_fixup(const float* __restrict__ x,
                                                 float* __restrict__ sparse,
                                                 float* __restrict__ pooled,
                                                 float* __restrict__ winner,
                                                 const uint32_t* __restrict__ wcount,
                                                 const uint32_t* __restrict__ wlist,
                                                 uint32_t cap) {
    uint32_t n = *wcount;
    if (n > cap) n = cap;
    for (uint32_t i = blockIdx.x * 256u + threadIdx.x; i < n; i += gridDim.x * 256u) {
        const uint32_t r    = wlist[i];
        const uint32_t bc   = r >> 12;          // r / 4096
        const uint32_t rem  = r & 4095u;
        const uint32_t prow = rem >> 6;
        const uint32_t pcol = rem & 63u;
        const size_t base = (size_t)bc * kImg + prow * 256u + pcol * 2u;
        float v0 = x[base], v1 = x[base + 1u], v2 = x[base + 128u], v3 = x[base + 129u];

        // exact reference chain (OCML expf/logf, IEEE div, same op order)
        float m  = fmaxf(fmaxf(fmaxf(fmaxf(v0, v1), v2), v3), 0.0f);
        float e0 = expf(v0 - m);
        float e1 = expf(v1 - m);
        float e2 = expf(v2 - m);
        float e3 = expf(v3 - m);
        float e4 = expf(0.0f - m);
        float den = ((((e0 + e1) + e2) + e3) + e4) + EPSF;
        float p0 = e0 / den, p1 = e1 / den, p2 = e2 / den, p3 = e3 / den, p4 = e4 / den;

        const uint32_t jb = r * 5u;
        float u0 = uniform_from_bits(jax_bits_partitionable(jb + 0u));
        float u1 = uniform_from_bits(jax_bits_partitionable(jb + 1u));
        float u2 = uniform_from_bits(jax_bits_partitionable(jb + 2u));
        float u3 = uniform_from_bits(jax_bits_partitionable(jb + 3u));
        float u4 = uniform_from_bits(jax_bits_partitionable(jb + 4u));
        float y0 = logf(p0 + EPSF) + (-logf(-logf(u0 + EPSF) + EPSF));
        float y1 = logf(p1 + EPSF) + (-logf(-logf(u1 + EPSF) + EPSF));
        float y2 = logf(p2 + EPSF) + (-logf(-logf(u2 + EPSF) + EPSF));
        float y3 = logf(p3 + EPSF) + (-logf(-logf(u3 + EPSF) + EPSF));
        float y4 = logf(p4 + EPSF) + (-logf(-logf(u4 + EPSF) + EPSF));
        int w = 0; float best = y0;
        if (y1 > best) { best = y1; w = 1; }
        if (y2 > best) { best = y2; w = 2; }
        if (y3 > best) { best = y3; w = 3; }
        if (y4 > best) { best = y4; w = 4; }
        float wp = (w == 0) ? p0 : (w == 1) ? p1 : (w == 2) ? p2 : (w == 3) ? p3 : p4;

        float* sp = sparse + base;
        sp[0]    = (w == 0) ? wp : 0.0f;
        sp[1]    = (w == 1) ? wp : 0.0f;
        sp[128]  = (w == 2) ? wp : 0.0f;
        sp[129]  = (w == 3) ? wp : 0.0f;
        pooled[r] = ((p0 + p1) + p2) + p3;
        winner[r] = (float)w;
    }
}

extern "C" void kernel_launch(void* const* d_in, const int* in_sizes, int n_in,
                              void* d_out, int out_size, void* d_ws, size_t ws_size,
                              hipStream_t stream) {
    (void)in_sizes; (void)n_in; (void)out_size;
    const float* x = (const float*)d_in[0];
    float* out = (float*)d_out;
    float* sparse = out;                       // [32,96,128,128]
    float* pooled = out + kSparseN;            // [32,96,64,64]
    float* winner = out + kSparseN + kPooledN; // [32,96,64,64] (indices as float)

    uint32_t* wcount = (uint32_t*)d_ws;
    uint32_t* wlist  = (uint32_t*)d_ws + 4;    // list starts at byte 16
    uint32_t cap = (ws_size > 16) ? (uint32_t)((ws_size - 16) / 4) : 0u;

    hipMemsetAsync(d_ws, 0, 4, stream);        // zero the counter (capturable)

    const uint32_t nThreads = kBC * 64u * 16u; // 3,145,728 ; 12288 blocks
    dim3 grid(nThreads / 256u), block(256u);
    hipLaunchKernelGGL(mmp_kernel, grid, block, 0, stream,
                       x, sparse, pooled, winner, wcount, wlist, cap);
    hipLaunchKernelGGL(mmp_fixup, dim3(128), dim3(256), 0, stream,
                       x, sparse, pooled, winner, wcount, wlist, cap);
}